// Round 1
// baseline (1254.897 us; speedup 1.0000x reference)
//
#include <hip/hip_runtime.h>
#include <math.h>

// Problem constants (from reference): B=64, N=14*14*32=6272, DIN=8, D=16, M=10, C=10
#define BATCH 64
#define NPOS 6272
#define DIN_ 8
#define DVEC 16
#define CCAP 10
#define JC 4                    // capsule positions per block
#define NBLK (NPOS / JC)        // 1568 blocks
#define PSTRIDE 1200            // padded partial row (floats)
#define ACC_FLOATS 1194         // S[160] + T[10] + ubar[64*16]
#define P_OFF 1280              // float offset of partials in ws

// ---------------------------------------------------------------------------
// Main kernel: per block, 4 j's x 64 b x 10 mm events.
//   lane = b (all winner logic lane-private), wave handles (jj,mm) combos.
//   Emits block partials: S (theta-weighted u sums per class), T (theta sums),
//   ubar (sum of squashed u over this block's n' for each b).
// ---------------------------------------------------------------------------
__global__ __launch_bounds__(256) void caps_main(
    const float* __restrict__ xin,   // [B][N][8]
    const float* __restrict__ Wg,    // [N][8][160]
    const float* __restrict__ dcg,   // [10][16]
    float* __restrict__ P,           // [NBLK][PSTRIDE] or nullptr
    float* __restrict__ ACC)         // [ACC_FLOATS] (atomic fallback)
{
    __shared__ __align__(16) float W_lds[JC * 1280];   // 20 KB
    __shared__ __align__(16) float x_lds[64 * 33];     // padded rows: conflict-free
    __shared__ __align__(16) float dc_lds[160];
    __shared__ float S_rep[8 * 173];                   // 8 replicas of S[10*17]+T in pad slot
    __shared__ float ub_lds[64 * 17];

    const int tid = threadIdx.x;
    const int j0 = blockIdx.x * JC;

    // ---- stage W chunk (coalesced float4) ----
    {
        const float4* wsrc = (const float4*)(Wg + (size_t)j0 * 1280);
        float4* wdst = (float4*)W_lds;
        #pragma unroll
        for (int s = 0; s < 5; ++s) wdst[tid + 256 * s] = wsrc[tid + 256 * s];
    }
    // ---- stage x: 64 b x 32 floats, scalar LDS stores into stride-33 rows ----
    #pragma unroll
    for (int s = 0; s < 2; ++s) {
        int idx = tid + 256 * s;            // 0..511
        int b = idx >> 3, p = idx & 7;
        const float* src = xin + (size_t)b * (NPOS * DIN_) + (size_t)j0 * DIN_ + p * 4;
        float4 v = *(const float4*)src;
        float* dst = &x_lds[b * 33 + p * 4];
        dst[0] = v.x; dst[1] = v.y; dst[2] = v.z; dst[3] = v.w;
    }
    if (tid < 40) ((float4*)dc_lds)[tid] = ((const float4*)dcg)[tid];
    for (int q = tid; q < 8 * 173; q += 256) S_rep[q] = 0.0f;
    for (int q = tid; q < 64 * 17; q += 256) ub_lds[q] = 0.0f;
    __syncthreads();

    const int lane = tid & 63;      // = b
    const int rep  = tid & 7;       // LDS scatter replica
    const int wv   = tid >> 6;      // wave id 0..3

    float ub[DVEC];
    #pragma unroll
    for (int d = 0; d < DVEC; ++d) ub[d] = 0.0f;

    for (int it = 0; it < 10; ++it) {
        const int q  = wv + 4 * it;     // 0..39 combo, disjoint across waves
        const int jj = q / 10;
        const int mm = q - 10 * jj;

        // x row into regs (2-way bank alias only — free)
        float xr[DIN_];
        #pragma unroll
        for (int i = 0; i < DIN_; ++i) xr[i] = x_lds[lane * 33 + jj * 8 + i];

        // u[16] = x (1x8) @ W_j[:, mm*16 .. mm*16+16)   (broadcast b128 W reads)
        float u[DVEC];
        #pragma unroll
        for (int d = 0; d < DVEC; ++d) u[d] = 0.0f;
        const float* wbase = &W_lds[jj * 1280 + mm * 16];
        #pragma unroll
        for (int i = 0; i < DIN_; ++i) {
            const float4* wr = (const float4*)(wbase + i * 160);
            #pragma unroll
            for (int d4 = 0; d4 < 4; ++d4) {
                float4 wvv = wr[d4];
                u[4 * d4 + 0] = fmaf(xr[i], wvv.x, u[4 * d4 + 0]);
                u[4 * d4 + 1] = fmaf(xr[i], wvv.y, u[4 * d4 + 1]);
                u[4 * d4 + 2] = fmaf(xr[i], wvv.z, u[4 * d4 + 2]);
                u[4 * d4 + 3] = fmaf(xr[i], wvv.w, u[4 * d4 + 3]);
            }
        }

        // squash: u *= tanh(|u|)/|u|
        float nsq = 0.0f;
        #pragma unroll
        for (int d = 0; d < DVEC; ++d) nsq = fmaf(u[d], u[d], nsq);
        float nrm = sqrtf(nsq);
        float sc = tanhf(nrm) / nrm;
        #pragma unroll
        for (int d = 0; d < DVEC; ++d) { u[d] *= sc; ub[d] += u[d]; }

        // sims vs the 10 digit caps (broadcast b128 dc reads)
        float s0[CCAP];
        #pragma unroll
        for (int c = 0; c < CCAP; ++c) {
            const float4* dcr = (const float4*)&dc_lds[c * 16];
            float acc = 0.0f;
            #pragma unroll
            for (int d4 = 0; d4 < 4; ++d4) {
                float4 dv = dcr[d4];
                acc = fmaf(u[4 * d4 + 0], dv.x, acc);
                acc = fmaf(u[4 * d4 + 1], dv.y, acc);
                acc = fmaf(u[4 * d4 + 2], dv.z, acc);
                acc = fmaf(u[4 * d4 + 3], dv.w, acc);
            }
            s0[c] = acc;
        }

        // exact reference semantics: sims = sim0*mask, argmax(first max), mask[w] -= 1
        float msk[CCAP];
        #pragma unroll
        for (int c = 0; c < CCAP; ++c) msk[c] = 1.0f;
        const float thetas[3] = {1.0f, 0.2f, 0.1f};
        #pragma unroll
        for (int t = 0; t < 3; ++t) {
            float best = s0[0] * msk[0];
            int win = 0;
            #pragma unroll
            for (int c = 1; c < CCAP; ++c) {
                float v = s0[c] * msk[c];
                if (v > best) { best = v; win = c; }
            }
            const float th = thetas[t];
            float* Sr = &S_rep[rep * 173 + win * 17];
            #pragma unroll
            for (int d = 0; d < DVEC; ++d) atomicAdd(&Sr[d], th * u[d]);
            atomicAdd(&Sr[16], th);   // T in the pad slot
            #pragma unroll
            for (int c = 0; c < CCAP; ++c) msk[c] -= (c == win) ? 1.0f : 0.0f;
        }
    }

    // per-lane ubar into LDS (2-way alias only)
    #pragma unroll
    for (int d = 0; d < DVEC; ++d) atomicAdd(&ub_lds[lane * 17 + d], ub[d]);
    __syncthreads();

    // ---- block epilogue: fold 8 replicas, emit 1194 partials ----
    if (P != nullptr) {
        float* prow = P + (size_t)blockIdx.x * PSTRIDE;
        for (int qq = tid; qq < ACC_FLOATS; qq += 256) {
            float v;
            if (qq < 160) {
                int c = qq >> 4, d = qq & 15;
                v = 0.0f;
                #pragma unroll
                for (int r = 0; r < 8; ++r) v += S_rep[r * 173 + c * 17 + d];
            } else if (qq < 170) {
                int c = qq - 160;
                v = 0.0f;
                #pragma unroll
                for (int r = 0; r < 8; ++r) v += S_rep[r * 173 + c * 17 + 16];
            } else {
                int x = qq - 170;
                v = ub_lds[(x >> 4) * 17 + (x & 15)];
            }
            prow[qq] = v;
        }
    } else {
        // fallback if ws too small: direct global atomics
        for (int qq = tid; qq < ACC_FLOATS; qq += 256) {
            float v;
            if (qq < 160) {
                int c = qq >> 4, d = qq & 15;
                v = 0.0f;
                #pragma unroll
                for (int r = 0; r < 8; ++r) v += S_rep[r * 173 + c * 17 + d];
            } else if (qq < 170) {
                int c = qq - 160;
                v = 0.0f;
                #pragma unroll
                for (int r = 0; r < 8; ++r) v += S_rep[r * 173 + c * 17 + 16];
            } else {
                int x = qq - 170;
                v = ub_lds[(x >> 4) * 17 + (x & 15)];
            }
            unsafeAtomicAdd(&ACC[qq], v);
        }
    }
}

// ---------------------------------------------------------------------------
// Reduce block partials: 98 blocks x 16 rows each (coalesced), atomic fold to ACC
// ---------------------------------------------------------------------------
__global__ __launch_bounds__(256) void caps_reduce(const float* __restrict__ P,
                                                   float* __restrict__ ACC)
{
    const int t = threadIdx.x;
    float acc[5] = {0.f, 0.f, 0.f, 0.f, 0.f};
    const int r0 = blockIdx.x * 16;
    for (int r = 0; r < 16; ++r) {
        const float* row = P + (size_t)(r0 + r) * PSTRIDE;
        #pragma unroll
        for (int s = 0; s < 5; ++s) {
            int col = t + 256 * s;
            float v = (col < ACC_FLOATS) ? row[col] : 0.0f;
            acc[s] += v;
        }
    }
    #pragma unroll
    for (int s = 0; s < 5; ++s) {
        int col = t + 256 * s;
        if (col < ACC_FLOATS) unsafeAtomicAdd(&ACC[col], acc[s]);
    }
}

// ---------------------------------------------------------------------------
// Finalize: dc update + row-normalize, logits = (ubar/Nm)·dc_new, softmax
// ---------------------------------------------------------------------------
__global__ __launch_bounds__(256) void caps_final(const float* __restrict__ ACC,
                                                  const float* __restrict__ dcg,
                                                  float* __restrict__ outp)
{
    __shared__ float dcn[160];
    __shared__ float rnm[10];
    __shared__ float lg[640];
    const int t = threadIdx.x;

    if (t < 160) {
        int c = t >> 4;
        float d0 = dcg[t];
        float upd = (ACC[t] - ACC[160 + c] * d0) * (float)(1.0 / 4014080.0); // /(B*N*m)
        dcn[t] = d0 + upd;
    }
    __syncthreads();
    if (t < 10) {
        float s = 0.0f;
        #pragma unroll
        for (int d = 0; d < 16; ++d) s += dcn[t * 16 + d] * dcn[t * 16 + d];
        rnm[t] = 1.0f / sqrtf(s);
    }
    __syncthreads();
    if (t < 160) dcn[t] *= rnm[t >> 4];
    __syncthreads();

    for (int q = t; q < 640; q += 256) {
        int b = q / 10, c = q - 10 * b;
        const float* ubp = &ACC[170 + b * 16];
        float s = 0.0f;
        #pragma unroll
        for (int d = 0; d < 16; ++d) s += ubp[d] * dcn[c * 16 + d];
        lg[q] = s * (float)(1.0 / 62720.0);   // mean over Nm
    }
    __syncthreads();
    if (t < 64) {
        float mx = lg[t * 10];
        #pragma unroll
        for (int c = 1; c < 10; ++c) mx = fmaxf(mx, lg[t * 10 + c]);
        float e[10];
        float ssum = 0.0f;
        #pragma unroll
        for (int c = 0; c < 10; ++c) { e[c] = expf(lg[t * 10 + c] - mx); ssum += e[c]; }
        float inv = 1.0f / ssum;
        #pragma unroll
        for (int c = 0; c < 10; ++c) outp[t * 10 + c] = e[c] * inv;
    }
}

extern "C" void kernel_launch(void* const* d_in, const int* in_sizes, int n_in,
                              void* d_out, int out_size, void* d_ws, size_t ws_size,
                              hipStream_t stream)
{
    const float* xin = (const float*)d_in[0];
    const float* Wg  = (const float*)d_in[1];
    const float* dcg = (const float*)d_in[2];
    float* outp = (float*)d_out;
    float* ws = (float*)d_ws;
    float* ACC = ws;

    const size_t need = (size_t)(P_OFF + (size_t)NBLK * PSTRIDE) * sizeof(float);
    float* P = (ws_size >= need) ? (ws + P_OFF) : nullptr;

    hipMemsetAsync(ACC, 0, ACC_FLOATS * sizeof(float), stream);
    caps_main<<<dim3(NBLK), dim3(256), 0, stream>>>(xin, Wg, dcg, P, ACC);
    if (P) caps_reduce<<<dim3(98), dim3(256), 0, stream>>>(P, ACC);
    caps_final<<<dim3(1), dim3(256), 0, stream>>>(ACC, dcg, outp);
}